// Round 2
// baseline (199.994 us; speedup 1.0000x reference)
//
#include <hip/hip_runtime.h>
#include <hip/hip_bf16.h>

#define BB 32
#define TT 8192
#define CC 3
#define NSS 256
#define LSS 32
#define JL (LSS * CC)        // 96 elements per shapelet
#define WW (TT - LSS + 1)    // 8161 windows
#define WTILE 1024
#define STILE 16
#define WT 4                 // windows per thread (strided by 256)
#define NTHREADS 256

__global__ __launch_bounds__(NTHREADS) void init_out_kernel(float* out, int n) {
  int i = blockIdx.x * blockDim.x + threadIdx.x;
  if (i < n) out[i] = __int_as_float(0x7F800000);  // +inf
}

__global__ __launch_bounds__(NTHREADS) void shapelet_kernel(
    const float* __restrict__ data, const float* __restrict__ kern,
    float* __restrict__ out) {
  __shared__ float sdata[(WTILE + LSS - 1) * CC];  // 3165 floats = 12.7 KB
  __shared__ float sk2[STILE];
  __shared__ float swmin[NTHREADS / 64][STILE];

  const int tid = threadIdx.x;
  const int wtile = blockIdx.x;
  const int stile = blockIdx.y;
  const int b = blockIdx.z;
  const int t0 = wtile * WTILE;
  const int sbase = stile * STILE;

  // ---- stage data slab for this (b, w-tile) into LDS (zero-pad past T) ----
  {
    const float* dptr = data + ((size_t)b * TT + t0) * CC;
    const int nelem = (WTILE + LSS - 1) * CC;       // 3165
    const int navail = (TT - t0) * CC;              // valid elements
    for (int i = tid; i < nelem; i += NTHREADS)
      sdata[i] = (i < navail) ? dptr[i] : 0.0f;
  }
  // ---- k2 for this shapelet tile ----
  if (tid < STILE) {
    const float* kp = kern + (size_t)(sbase + tid) * JL;
    float a = 0.0f;
    #pragma unroll
    for (int j = 0; j < JL; ++j) a = fmaf(kp[j], kp[j], a);
    sk2[tid] = a;
  }
  __syncthreads();

  // ---- main cross-correlation loop ----
  float acc[WT][STILE];
  float a2[WT];
  #pragma unroll
  for (int i = 0; i < WT; ++i) {
    a2[i] = 0.0f;
    #pragma unroll
    for (int s = 0; s < STILE; ++s) acc[i][s] = 0.0f;
  }

  const float* kp = kern + (size_t)sbase * JL;  // uniform -> s_load
  const int base = tid * CC;

  #pragma unroll 4
  for (int j = 0; j < JL; ++j) {
    float d[WT];
    #pragma unroll
    for (int i = 0; i < WT; ++i) {
      d[i] = sdata[base + i * ((WTILE / WT) * CC) + j];  // stride 768
      a2[i] = fmaf(d[i], d[i], a2[i]);
    }
    #pragma unroll
    for (int s = 0; s < STILE; ++s) {
      const float kv = kp[s * JL + j];  // wave-uniform scalar load
      #pragma unroll
      for (int i = 0; i < WT; ++i)
        acc[i][s] = fmaf(d[i], kv, acc[i][s]);
    }
  }

  // ---- per-thread min over its windows ----
  float k2r[STILE];
  #pragma unroll
  for (int s = 0; s < STILE; ++s) k2r[s] = sk2[s];

  float localmin[STILE];
  #pragma unroll
  for (int s = 0; s < STILE; ++s) localmin[s] = __int_as_float(0x7F800000);

  #pragma unroll
  for (int i = 0; i < WT; ++i) {
    const int w = t0 + tid + i * (WTILE / WT);
    if (w < WW) {
      #pragma unroll
      for (int s = 0; s < STILE; ++s) {
        const float dist = a2[i] + k2r[s] - 2.0f * acc[i][s];
        localmin[s] = fminf(localmin[s], dist);
      }
    }
  }

  // ---- 64-lane butterfly min ----
  #pragma unroll
  for (int s = 0; s < STILE; ++s) {
    float v = localmin[s];
    for (int m = 32; m >= 1; m >>= 1)
      v = fminf(v, __shfl_xor(v, m, 64));
    localmin[s] = v;
  }

  const int wave = tid >> 6;
  const int lane = tid & 63;
  if (lane == 0) {
    #pragma unroll
    for (int s = 0; s < STILE; ++s) swmin[wave][s] = localmin[s];
  }
  __syncthreads();

  if (tid < STILE) {
    float m = swmin[0][tid];
    #pragma unroll
    for (int wv = 1; wv < NTHREADS / 64; ++wv) m = fminf(m, swmin[wv][tid]);
    m *= (1.0f / LSS);
    atomicMin((int*)out + ((size_t)b * NSS + sbase + tid), __float_as_int(m));
  }
}

extern "C" void kernel_launch(void* const* d_in, const int* in_sizes, int n_in,
                              void* d_out, int out_size, void* d_ws, size_t ws_size,
                              hipStream_t stream) {
  const float* data = (const float*)d_in[0];
  const float* kern = (const float*)d_in[1];
  float* out = (float*)d_out;

  hipLaunchKernelGGL(init_out_kernel, dim3((BB * NSS + NTHREADS - 1) / NTHREADS),
                     dim3(NTHREADS), 0, stream, out, BB * NSS);

  dim3 grid((WW + WTILE - 1) / WTILE, NSS / STILE, BB);  // (8, 16, 32)
  hipLaunchKernelGGL(shapelet_kernel, grid, dim3(NTHREADS), 0, stream,
                     data, kern, out);
}

// Round 6
// 80.217 us; speedup vs baseline: 2.4932x; 2.4932x over previous
//
#include <hip/hip_runtime.h>
#include <hip/hip_bf16.h>

#define BB 32
#define TT 8192
#define CC 3
#define NSS 256
#define LSS 32
#define JL (LSS * CC)            // 96
#define WW (TT - LSS + 1)        // 8161
#define WTILE 512
#define NWTILE (TT / WTILE)      // 16 wtiles x 512 = 8192 windows (tail masked)
#define NE (WTILE * CC + JL - CC)  // 1629 staged elements
#define NPK (NE - 1)             // 1628 packed pairs
#define NP 1793                  // prefix array (256*7+1)
#define NTHREADS 256
#define PER_T 7
#define INFBITS 0x7F800000

typedef __attribute__((ext_vector_type(8))) short bf16x8;
typedef __attribute__((ext_vector_type(16))) float f32x16;
typedef __attribute__((ext_vector_type(4))) unsigned int uint4v;

__device__ __forceinline__ unsigned int bf16pk(float a, float b) {
  unsigned ua = __float_as_uint(a), ub = __float_as_uint(b);
  ua = (ua + 0x7FFFu + ((ua >> 16) & 1u)) >> 16;   // RNE round to bf16
  ub = (ub + 0x7FFFu + ((ub >> 16) & 1u)) >> 16;
  return ua | (ub << 16);
}

__device__ __forceinline__ bf16x8 mk8(unsigned u0, unsigned u1, unsigned u2, unsigned u3) {
  uint4v u = {u0, u1, u2, u3};
  return __builtin_bit_cast(bf16x8, u);
}

__global__ __launch_bounds__(NTHREADS) void init_out_kernel(float* out, int n) {
  int i = blockIdx.x * blockDim.x + threadIdx.x;
  if (i < n) out[i] = __int_as_float(INFBITS);
}

__global__ __launch_bounds__(NTHREADS, 2) void shapelet_mfma_kernel(
    const float* __restrict__ data, const float* __restrict__ kern,
    float* __restrict__ out) {
  __shared__ unsigned int spk[NPK];   // packed bf16 sliding pairs
  __shared__ float p[NP];             // exclusive prefix of squares
  __shared__ float a2[WTILE];         // window norms (+inf for invalid)
  __shared__ float k2arr[NSS];
  __shared__ float wsum[4];
  __shared__ float fin[4][4][32];     // [wave][nf][col]

  const int tid  = threadIdx.x;
  const int lane = tid & 63;
  const int wave = tid >> 6;
  const int wn = wave & 1;   // N-half (128 shapelets)
  const int wm = wave >> 1;  // M interleave
  const int wt = blockIdx.x;
  const int b  = blockIdx.y;
  const int t0 = wt * WTILE;
  const long ebase = (long)b * (TT * CC) + (long)t0 * CC;
  const int evalid = (TT - t0) * CC;  // elements left in this batch row

  // ---- stage 8 elements/thread; build packed pairs + squares ----
  float e[PER_T + 1], sq[PER_T];
  float part = 0.f;
  const int i0 = tid * PER_T;
  #pragma unroll
  for (int r = 0; r < PER_T + 1; ++r) {
    const int i = i0 + r;
    float v = 0.f;
    if (i < NE && i < evalid) v = data[ebase + i];
    e[r] = v;
  }
  #pragma unroll
  for (int r = 0; r < PER_T; ++r) { sq[r] = e[r] * e[r]; part += sq[r]; }
  #pragma unroll
  for (int r = 0; r < PER_T; ++r) {
    const int i = i0 + r;
    if (i < NPK) spk[i] = bf16pk(e[r], e[r + 1]);
  }

  // ---- wave-level inclusive scan of per-thread partial sums ----
  float incl = part;
  #pragma unroll
  for (int m = 1; m < 64; m <<= 1) {
    float o = __shfl_up(incl, m, 64);
    if (lane >= m) incl += o;
  }
  if (lane == 63) wsum[wave] = incl;

  // ---- k2 per shapelet (independent of LDS above) ----
  {
    const float* kp = kern + tid * JL;
    float acc = 0.f;
    #pragma unroll
    for (int j = 0; j < JL; j += 4) {
      float4 v = *reinterpret_cast<const float4*>(kp + j);
      acc = fmaf(v.x, v.x, fmaf(v.y, v.y, fmaf(v.z, v.z, fmaf(v.w, v.w, acc))));
    }
    k2arr[tid] = acc;
  }
  __syncthreads();

  // ---- write exclusive prefix values ----
  {
    float woff = 0.f;
    for (int wv = 0; wv < wave; ++wv) woff += wsum[wv];
    float run = woff + (incl - part);
    #pragma unroll
    for (int r = 0; r < PER_T; ++r) { p[i0 + r] = run; run += sq[r]; }
  }

  // ---- B fragments: all K=96 for this wave's 128 shapelets, in registers ----
  bf16x8 bfr[6][4];
  {
    const int col = lane & 31, g = lane >> 5;
    #pragma unroll
    for (int ks = 0; ks < 6; ++ks) {
      #pragma unroll
      for (int nf = 0; nf < 4; ++nf) {
        const int s = wn * 128 + nf * 32 + col;
        const float* kp = kern + s * JL + ks * 16 + g * 8;
        float4 x = *reinterpret_cast<const float4*>(kp);
        float4 y = *reinterpret_cast<const float4*>(kp + 4);
        bfr[ks][nf] = mk8(bf16pk(x.x, x.y), bf16pk(x.z, x.w),
                          bf16pk(y.x, y.y), bf16pk(y.z, y.w));
      }
    }
  }
  __syncthreads();

  // ---- a2 from prefix diffs; +inf masks invalid tail windows ----
  for (int w = tid; w < WTILE; w += NTHREADS) {
    const int gw = t0 + w;
    a2[w] = (gw < WW) ? (p[3 * w + JL] - p[3 * w]) : __int_as_float(INFBITS);
  }
  __syncthreads();

  // ---- main MFMA loop over M-tiles of 32 windows ----
  const int mrow = lane & 31, hi = lane >> 5;
  const int lb = 3 * mrow + 8 * hi;
  const float INF = __int_as_float(INFBITS);
  float runmin[4] = {INF, INF, INF, INF};
  f32x16 z16 = {0.f};

  for (int mt = wm; mt < WTILE / 32; mt += 2) {
    const int q0 = mt * JL + lb;
    bf16x8 af[6];
    #pragma unroll
    for (int ks = 0; ks < 6; ++ks) {
      const int q = q0 + ks * 16;
      af[ks] = mk8(spk[q], spk[q + 2], spk[q + 4], spk[q + 6]);
    }
    f32x16 acc[4];
    #pragma unroll
    for (int nf = 0; nf < 4; ++nf)
      acc[nf] = __builtin_amdgcn_mfma_f32_32x32x16_bf16(af[0], bfr[0][nf], z16, 0, 0, 0);
    #pragma unroll
    for (int ks = 1; ks < 6; ++ks) {
      #pragma unroll
      for (int nf = 0; nf < 4; ++nf)
        acc[nf] = __builtin_amdgcn_mfma_f32_32x32x16_bf16(af[ks], bfr[ks][nf], acc[nf], 0, 0, 0);
    }
    float a2r[16];
    #pragma unroll
    for (int r = 0; r < 16; ++r)
      a2r[r] = a2[mt * 32 + (r & 3) + 8 * (r >> 2) + 4 * hi];
    #pragma unroll
    for (int nf = 0; nf < 4; ++nf) {
      #pragma unroll
      for (int r = 0; r < 16; ++r)
        runmin[nf] = fminf(runmin[nf], fmaf(-2.f, acc[nf][r], a2r[r]));
    }
  }

  // ---- reduce: lanes l, l+32 share shapelet col ----
  #pragma unroll
  for (int nf = 0; nf < 4; ++nf) {
    float v = runmin[nf];
    v = fminf(v, __shfl_xor(v, 32, 64));
    if (lane < 32) fin[wave][nf][lane] = v;
  }
  __syncthreads();

  {
    const int wn_o = tid >> 7, nf_o = (tid >> 5) & 3, col = tid & 31;
    const float v = fminf(fin[wn_o][nf_o][col], fin[wn_o + 2][nf_o][col]);
    const int s = wn_o * 128 + nf_o * 32 + col;
    const float res = (v + k2arr[s]) * (1.0f / 32.0f);
    atomicMin((int*)out + ((long)b * NSS + s), __float_as_int(res));
  }
}

extern "C" void kernel_launch(void* const* d_in, const int* in_sizes, int n_in,
                              void* d_out, int out_size, void* d_ws, size_t ws_size,
                              hipStream_t stream) {
  const float* data = (const float*)d_in[0];
  const float* kern = (const float*)d_in[1];
  float* out = (float*)d_out;

  hipLaunchKernelGGL(init_out_kernel, dim3((BB * NSS + NTHREADS - 1) / NTHREADS),
                     dim3(NTHREADS), 0, stream, out, BB * NSS);

  dim3 grid(NWTILE, BB);  // (16, 32) = 512 blocks
  hipLaunchKernelGGL(shapelet_mfma_kernel, grid, dim3(NTHREADS), 0, stream,
                     data, kern, out);
}

// Round 10
// 76.915 us; speedup vs baseline: 2.6002x; 1.0429x over previous
//
#include <hip/hip_runtime.h>
#include <hip/hip_bf16.h>

#define BB 32
#define TT 8192
#define CC 3
#define NSS 256
#define LSS 32
#define JL (LSS * CC)            // 96
#define WW (TT - LSS + 1)        // 8161
#define WTILE 512
#define NWTILE (TT / WTILE)      // 16
#define ROWW (TT * CC)           // 24576 elements per batch row
#define NE2 1629                 // staged floats per slab (prep)
#define NPK2 1628                // packed words per slab
#define SPK_ROWS 33              // 32 + phantom row for b=31 over-read
#define NTHREADS 256
#define INFBITS 0x7F800000
#define NEGINFBITS 0xFF800000

typedef __attribute__((ext_vector_type(8))) short bf16x8;
typedef __attribute__((ext_vector_type(16))) float f32x16;

__device__ __forceinline__ unsigned int bf16pk(float a, float b) {
  unsigned ua = __float_as_uint(a), ub = __float_as_uint(b);
  ua = (ua + 0x7FFFu + ((ua >> 16) & 1u)) >> 16;   // RNE round to bf16
  ub = (ub + 0x7FFFu + ((ub >> 16) & 1u)) >> 16;
  return ua | (ub << 16);
}

__device__ __forceinline__ bf16x8 mk8(unsigned u0, unsigned u1, unsigned u2, unsigned u3) {
  union { unsigned u[4]; bf16x8 v; } c;
  c.u[0] = u0; c.u[1] = u1; c.u[2] = u2; c.u[3] = u3;
  return c.v;
}

// ---------------- prep: pack data pairs, a2, fragment-ordered B, k2, out-init --
__global__ __launch_bounds__(NTHREADS) void prep_kernel(
    const float* __restrict__ data, const float* __restrict__ kernm,
    unsigned int* __restrict__ spk_g, float* __restrict__ a2_g,
    uint4* __restrict__ kpk_g, float* __restrict__ k2_g,
    float* __restrict__ out) {
  const int tid = threadIdx.x;
  const int x = blockIdx.x, b = blockIdx.y;

  if (x == NWTILE) {            // B-pack block (only b==0)
    if (b != 0) return;
    const int s = tid;
    const float* kp = kernm + s * JL;
    float f[JL];
    float acc = 0.f;
    #pragma unroll
    for (int j = 0; j < JL; j += 4) {
      float4 v = *reinterpret_cast<const float4*>(kp + j);
      f[j] = v.x; f[j + 1] = v.y; f[j + 2] = v.z; f[j + 3] = v.w;
      acc = fmaf(v.x, v.x, fmaf(v.y, v.y, fmaf(v.z, v.z, fmaf(v.w, v.w, acc))));
    }
    k2_g[s] = acc;
    const int wn = s >> 7, nf = (s >> 5) & 3, col = s & 31;
    #pragma unroll
    for (int ks = 0; ks < 6; ++ks) {
      #pragma unroll
      for (int g = 0; g < 2; ++g) {
        const float* q = f + ks * 16 + g * 8;
        uint4 u;
        u.x = bf16pk(q[0], q[1]); u.y = bf16pk(q[2], q[3]);
        u.z = bf16pk(q[4], q[5]); u.w = bf16pk(q[6], q[7]);
        kpk_g[((wn * 6 + ks) * 4 + nf) * 64 + g * 32 + col] = u;
      }
    }
    for (int i = tid; i < BB * NSS; i += NTHREADS)
      out[i] = __int_as_float(INFBITS);
    return;
  }

  // slab block: pack pairs + window norms for (b, wtile x)
  __shared__ float e[NE2];
  const int t0 = x * WTILE;
  const int base = 3 * t0;
  const float* drow = data + (size_t)b * ROWW;
  for (int i = tid; i < NE2; i += NTHREADS) {
    const int gi = base + i;
    e[i] = (gi < ROWW) ? drow[gi] : 0.f;
  }
  __syncthreads();

  unsigned int* srow = spk_g + (size_t)b * ROWW;
  for (int i = tid; i < NPK2; i += NTHREADS) {
    const int j = base + i;
    if (j < ROWW - 1) srow[j] = bf16pk(e[i], e[i + 1]);
  }
  float* arow = a2_g + (size_t)b * TT;
  for (int wl = tid; wl < WTILE; wl += NTHREADS) {
    const int gw = t0 + wl;
    if (gw < WW) {
      float sum = 0.f;
      for (int j = 0; j < JL; ++j) { const float v = e[3 * wl + j]; sum = fmaf(v, v, sum); }
      arow[gw] = sum;
    } else {
      arow[gw] = __int_as_float(INFBITS);
    }
  }
}

// ---------------- main: MFMA cross-correlation + min ---------------------------
__global__ __launch_bounds__(NTHREADS, 2) void shapelet_main(
    const unsigned int* __restrict__ spk_g, const float* __restrict__ a2_g,
    const uint4* __restrict__ kpk_g, const float* __restrict__ k2_g,
    float* __restrict__ out) {
  __shared__ unsigned int spk[NPK2];
  __shared__ float ha2[WTILE];
  __shared__ float fin[4][4][32];

  const int tid = threadIdx.x, lane = tid & 63, wave = tid >> 6;
  const int wn = wave & 1, wm = wave >> 1;
  const int wt = blockIdx.x, b = blockIdx.y;
  const int t0 = wt * WTILE;

  // B fragments: 24 coalesced dwordx4 from fragment-ordered pack
  bf16x8 bfr[6][4];
  #pragma unroll
  for (int ks = 0; ks < 6; ++ks) {
    #pragma unroll
    for (int nf = 0; nf < 4; ++nf) {
      const uint4 u = kpk_g[((wn * 6 + ks) * 4 + nf) * 64 + lane];
      bfr[ks][nf] = mk8(u.x, u.y, u.z, u.w);
    }
  }

  // stage packed slab + window norms (coalesced)
  const unsigned int* srow = spk_g + (size_t)b * ROWW + 3 * t0;
  for (int i = tid; i < NPK2; i += NTHREADS) spk[i] = srow[i];
  const float* arow = a2_g + (size_t)b * TT + t0;
  ha2[tid] = arow[tid];
  ha2[tid + NTHREADS] = arow[tid + NTHREADS];
  __syncthreads();

  const int mrow = lane & 31, hi = lane >> 5;
  const int lb = 3 * mrow + 8 * hi;
  const float NEGINF = __int_as_float(NEGINFBITS);
  float runmax[4] = {NEGINF, NEGINF, NEGINF, NEGINF};

  #pragma unroll 1
  for (int mt = wm; mt < WTILE / 32; mt += 2) {
    const int q0 = mt * JL + lb;
    bf16x8 af[6];
    #pragma unroll
    for (int ks = 0; ks < 6; ++ks) {
      const int q = q0 + ks * 16;
      af[ks] = mk8(spk[q], spk[q + 2], spk[q + 4], spk[q + 6]);
    }
    f32x16 z16 = {0.f};
    f32x16 acc[4];
    #pragma unroll
    for (int nf = 0; nf < 4; ++nf)
      acc[nf] = __builtin_amdgcn_mfma_f32_32x32x16_bf16(af[0], bfr[0][nf], z16, 0, 0, 0);
    #pragma unroll
    for (int ks = 1; ks < 6; ++ks) {
      #pragma unroll
      for (int nf = 0; nf < 4; ++nf)
        acc[nf] = __builtin_amdgcn_mfma_f32_32x32x16_bf16(af[ks], bfr[ks][nf], acc[nf], 0, 0, 0);
    }
    float4 ar[4];
    #pragma unroll
    for (int k = 0; k < 4; ++k)
      ar[k] = *reinterpret_cast<const float4*>(&ha2[mt * 32 + 4 * hi + 8 * k]);
    #pragma unroll
    for (int nf = 0; nf < 4; ++nf) {
      #pragma unroll
      for (int k = 0; k < 4; ++k) {
        const float v0 = fmaf(-0.5f, ar[k].x, acc[nf][4 * k + 0]);
        const float v1 = fmaf(-0.5f, ar[k].y, acc[nf][4 * k + 1]);
        const float v2 = fmaf(-0.5f, ar[k].z, acc[nf][4 * k + 2]);
        const float v3 = fmaf(-0.5f, ar[k].w, acc[nf][4 * k + 3]);
        runmax[nf] = fmaxf(runmax[nf], fmaxf(fmaxf(v0, v1), fmaxf(v2, v3)));
      }
    }
  }

  // reduce: lanes l, l+32 share shapelet col; then across wm pairs
  #pragma unroll
  for (int nf = 0; nf < 4; ++nf) {
    float v = runmax[nf];
    v = fmaxf(v, __shfl_xor(v, 32, 64));
    if (lane < 32) fin[wave][nf][lane] = v;
  }
  __syncthreads();

  {
    const int wn_o = tid >> 7, nf_o = (tid >> 5) & 3, col = tid & 31;
    const float M = fmaxf(fin[wn_o][nf_o][col], fin[wn_o + 2][nf_o][col]);
    // s = wn_o*128 + nf_o*32 + col == tid
    const float res = fmaf(-2.f, M, k2_g[tid]) * (1.0f / 32.0f);
    atomicMin((int*)out + ((size_t)b * NSS + tid), __float_as_int(res));
  }
}

extern "C" void kernel_launch(void* const* d_in, const int* in_sizes, int n_in,
                              void* d_out, int out_size, void* d_ws, size_t ws_size,
                              hipStream_t stream) {
  const float* data = (const float*)d_in[0];
  const float* kern = (const float*)d_in[1];
  float* out = (float*)d_out;

  // workspace layout (16B-aligned)
  unsigned int* spk_g = (unsigned int*)d_ws;                       // 33*24576 words
  char* base = (char*)d_ws;
  float* a2_g = (float*)(base + (size_t)SPK_ROWS * ROWW * 4);      // 32*8192 floats
  uint4* kpk_g = (uint4*)(base + (size_t)SPK_ROWS * ROWW * 4 + (size_t)BB * TT * 4);
  float* k2_g  = (float*)((char*)kpk_g + 3072 * 16);               // 256 floats

  hipLaunchKernelGGL(prep_kernel, dim3(NWTILE + 1, BB), dim3(NTHREADS), 0, stream,
                     data, kern, spk_g, a2_g, kpk_g, k2_g, out);
  hipLaunchKernelGGL(shapelet_main, dim3(NWTILE, BB), dim3(NTHREADS), 0, stream,
                     spk_g, a2_g, kpk_g, k2_g, out);
}

// Round 13
// 74.416 us; speedup vs baseline: 2.6875x; 1.0336x over previous
//
#include <hip/hip_runtime.h>
#include <hip/hip_bf16.h>

#define BB 32
#define TT 8192
#define CC 3
#define NSS 256
#define LSS 32
#define JL (LSS * CC)            // 96
#define WW (TT - LSS + 1)        // 8161
#define WTILE 512
#define NWTILE (TT / WTILE)      // 16
#define ROWW (TT * CC)           // 24576 elements per batch row
#define NE2 1629                 // staged floats per slab (prep)
#define NPK2 1628                // packed words per slab
#define SPK_ROWS 33              // 32 + phantom row for b=31 over-read
#define NTHREADS 256
#define INFBITS 0x7F800000
#define NEGINFBITS 0xFF800000

typedef __attribute__((ext_vector_type(8))) short bf16x8;
typedef __attribute__((ext_vector_type(16))) float f32x16;
typedef __attribute__((ext_vector_type(4))) unsigned int uint4v;

__device__ __forceinline__ unsigned int bf16pk(float a, float b) {
  unsigned ua = __float_as_uint(a), ub = __float_as_uint(b);
  ua = (ua + 0x7FFFu + ((ua >> 16) & 1u)) >> 16;   // RNE round to bf16
  ub = (ub + 0x7FFFu + ((ub >> 16) & 1u)) >> 16;
  return ua | (ub << 16);
}

__device__ __forceinline__ bf16x8 mk8(unsigned u0, unsigned u1, unsigned u2, unsigned u3) {
  uint4v u = {u0, u1, u2, u3};
  return __builtin_bit_cast(bf16x8, u);
}

// ---------------- prep: pack data pairs, a2, fragment-ordered B, k2, out-init --
__global__ __launch_bounds__(NTHREADS) void prep_kernel(
    const float* __restrict__ data, const float* __restrict__ kernm,
    unsigned int* __restrict__ spk_g, float* __restrict__ a2_g,
    uint4* __restrict__ kpk_g, float* __restrict__ k2_g,
    float* __restrict__ out) {
  const int tid = threadIdx.x;
  const int x = blockIdx.x, b = blockIdx.y;

  if (x == NWTILE) {            // B-pack block (only b==0)
    if (b != 0) return;
    const int s = tid;
    const float* kp = kernm + s * JL;
    float f[JL];
    float acc = 0.f;
    #pragma unroll
    for (int j = 0; j < JL; j += 4) {
      float4 v = *reinterpret_cast<const float4*>(kp + j);
      f[j] = v.x; f[j + 1] = v.y; f[j + 2] = v.z; f[j + 3] = v.w;
      acc = fmaf(v.x, v.x, fmaf(v.y, v.y, fmaf(v.z, v.z, fmaf(v.w, v.w, acc))));
    }
    k2_g[s] = acc;
    const int wn = s >> 7, nf = (s >> 5) & 3, col = s & 31;
    #pragma unroll
    for (int ks = 0; ks < 6; ++ks) {
      #pragma unroll
      for (int g = 0; g < 2; ++g) {
        const float* q = f + ks * 16 + g * 8;
        uint4 u;
        u.x = bf16pk(q[0], q[1]); u.y = bf16pk(q[2], q[3]);
        u.z = bf16pk(q[4], q[5]); u.w = bf16pk(q[6], q[7]);
        kpk_g[((wn * 6 + ks) * 4 + nf) * 64 + g * 32 + col] = u;
      }
    }
    for (int i = tid; i < BB * NSS; i += NTHREADS)
      out[i] = __int_as_float(INFBITS);
    return;
  }

  // slab block: pack pairs + window norms for (b, wtile x)
  __shared__ float e[NE2];
  const int t0 = x * WTILE;
  const int base = 3 * t0;
  const float* drow = data + (size_t)b * ROWW;
  for (int i = tid; i < NE2; i += NTHREADS) {
    const int gi = base + i;
    e[i] = (gi < ROWW) ? drow[gi] : 0.f;
  }
  __syncthreads();

  unsigned int* srow = spk_g + (size_t)b * ROWW;
  for (int i = tid; i < NPK2; i += NTHREADS) {
    const int j = base + i;
    if (j < ROWW - 1) srow[j] = bf16pk(e[i], e[i + 1]);
  }
  float* arow = a2_g + (size_t)b * TT;
  for (int wl = tid; wl < WTILE; wl += NTHREADS) {
    const int gw = t0 + wl;
    if (gw < WW) {
      float sum = 0.f;
      for (int j = 0; j < JL; ++j) { const float v = e[3 * wl + j]; sum = fmaf(v, v, sum); }
      arow[gw] = sum;
    } else {
      arow[gw] = __int_as_float(INFBITS);
    }
  }
}

// ---------------- main: MFMA cross-correlation + min ---------------------------
// Register-lean variant: 2 N-frags per wave (64 shapelets), shapelet range
// split across blockIdx.y. Live VGPR target ~165 (vs ~230 at 4 N-frags).
__global__ __launch_bounds__(NTHREADS, 2) void shapelet_main(
    const unsigned int* __restrict__ spk_g, const float* __restrict__ a2_g,
    const uint4* __restrict__ kpk_g, const float* __restrict__ k2_g,
    float* __restrict__ out) {
  __shared__ unsigned int spk[NPK2];
  __shared__ float ha2[WTILE];
  __shared__ float fin[4][2][32];

  const int tid = threadIdx.x, lane = tid & 63, wave = tid >> 6;
  const int wn = wave & 1, wm = wave >> 1;
  const int wt = blockIdx.x, shx = blockIdx.y, b = blockIdx.z;
  const int t0 = wt * WTILE;

  // B fragments: 12 coalesced dwordx4 from fragment-ordered pack
  bf16x8 bfr[6][2];
  #pragma unroll
  for (int ks = 0; ks < 6; ++ks) {
    #pragma unroll
    for (int nf = 0; nf < 2; ++nf) {
      const uint4 u = kpk_g[((shx * 6 + ks) * 4 + (wn * 2 + nf)) * 64 + lane];
      bfr[ks][nf] = mk8(u.x, u.y, u.z, u.w);
    }
  }

  // stage packed slab + window norms (coalesced)
  const unsigned int* srow = spk_g + (size_t)b * ROWW + 3 * t0;
  for (int i = tid; i < NPK2; i += NTHREADS) spk[i] = srow[i];
  const float* arow = a2_g + (size_t)b * TT + t0;
  ha2[tid] = arow[tid];
  ha2[tid + NTHREADS] = arow[tid + NTHREADS];
  __syncthreads();

  const int mrow = lane & 31, hi = lane >> 5;
  const int lb = 3 * mrow + 8 * hi;
  const float NEGINF = __int_as_float(NEGINFBITS);
  float runmax[2] = {NEGINF, NEGINF};
  const f32x16 z16 = {0.f};

  #pragma unroll 1
  for (int mt = wm; mt < WTILE / 32; mt += 2) {
    const int q0 = mt * JL + lb;
    bf16x8 af[6];
    #pragma unroll
    for (int ks = 0; ks < 6; ++ks) {
      const int q = q0 + ks * 16;
      af[ks] = mk8(spk[q], spk[q + 2], spk[q + 4], spk[q + 6]);
    }
    f32x16 acc[2];
    #pragma unroll
    for (int nf = 0; nf < 2; ++nf)
      acc[nf] = __builtin_amdgcn_mfma_f32_32x32x16_bf16(af[0], bfr[0][nf], z16, 0, 0, 0);
    #pragma unroll
    for (int ks = 1; ks < 6; ++ks) {
      #pragma unroll
      for (int nf = 0; nf < 2; ++nf)
        acc[nf] = __builtin_amdgcn_mfma_f32_32x32x16_bf16(af[ks], bfr[ks][nf], acc[nf], 0, 0, 0);
    }
    float4 ar[4];
    #pragma unroll
    for (int k = 0; k < 4; ++k)
      ar[k] = *reinterpret_cast<const float4*>(&ha2[mt * 32 + 4 * hi + 8 * k]);
    #pragma unroll
    for (int nf = 0; nf < 2; ++nf) {
      #pragma unroll
      for (int k = 0; k < 4; ++k) {
        const float v0 = fmaf(-0.5f, ar[k].x, acc[nf][4 * k + 0]);
        const float v1 = fmaf(-0.5f, ar[k].y, acc[nf][4 * k + 1]);
        const float v2 = fmaf(-0.5f, ar[k].z, acc[nf][4 * k + 2]);
        const float v3 = fmaf(-0.5f, ar[k].w, acc[nf][4 * k + 3]);
        runmax[nf] = fmaxf(runmax[nf], fmaxf(fmaxf(v0, v1), fmaxf(v2, v3)));
      }
    }
  }

  // reduce: lanes l, l+32 share shapelet col; then across wm pairs
  #pragma unroll
  for (int nf = 0; nf < 2; ++nf) {
    float v = runmax[nf];
    v = fmaxf(v, __shfl_xor(v, 32, 64));
    if (lane < 32) fin[wave][nf][lane] = v;
  }
  __syncthreads();

  if (tid < 128) {
    const int wn_o = tid >> 6, nf_o = (tid >> 5) & 1, col = tid & 31;
    const float M = fmaxf(fin[wn_o][nf_o][col], fin[wn_o + 2][nf_o][col]);
    const int s = shx * 128 + tid;  // == shx*128 + wn_o*64 + nf_o*32 + col
    const float res = fmaf(-2.f, M, k2_g[s]) * (1.0f / 32.0f);
    atomicMin((int*)out + ((size_t)b * NSS + s), __float_as_int(res));
  }
}

extern "C" void kernel_launch(void* const* d_in, const int* in_sizes, int n_in,
                              void* d_out, int out_size, void* d_ws, size_t ws_size,
                              hipStream_t stream) {
  const float* data = (const float*)d_in[0];
  const float* kern = (const float*)d_in[1];
  float* out = (float*)d_out;

  // workspace layout (16B-aligned)
  unsigned int* spk_g = (unsigned int*)d_ws;                       // 33*24576 words
  char* base = (char*)d_ws;
  float* a2_g = (float*)(base + (size_t)SPK_ROWS * ROWW * 4);      // 32*8192 floats
  uint4* kpk_g = (uint4*)(base + (size_t)SPK_ROWS * ROWW * 4 + (size_t)BB * TT * 4);
  float* k2_g  = (float*)((char*)kpk_g + 3072 * 16);               // 256 floats

  hipLaunchKernelGGL(prep_kernel, dim3(NWTILE + 1, BB), dim3(NTHREADS), 0, stream,
                     data, kern, spk_g, a2_g, kpk_g, k2_g, out);
  hipLaunchKernelGGL(shapelet_main, dim3(NWTILE, 2, BB), dim3(NTHREADS), 0, stream,
                     spk_g, a2_g, kpk_g, k2_g, out);
}